// Round 10
// baseline (65.451 us; speedup 1.0000x reference)
//
#include <hip/hip_runtime.h>

constexpr int H = 192, W = 192, D = 192;
constexpr int N = H * W * D;

// 8-byte pair with only 4-byte alignment guarantee (z offset has arbitrary parity).
struct __attribute__((aligned(4))) f2u { float x, y; };

__global__ __launch_bounds__(256) void st_gather(
    const float* __restrict__ I,
    const float* __restrict__ dxt,
    const float* __restrict__ dyt,
    const float* __restrict__ dzt,
    float* __restrict__ out)
{
    int t = blockIdx.x * blockDim.x + threadIdx.x;   // N/4 threads exactly
    int base = t * 4;
    int d0 = base % D;            // 4 consecutive z share (h,w)
    int hw = base / D;
    int w = hw % W;
    int h = hw / W;

    float4 vx = reinterpret_cast<const float4*>(dxt)[t];
    float4 vy = reinterpret_cast<const float4*>(dyt)[t];
    float4 vz = reinterpret_cast<const float4*>(dzt)[t];

    float rx[4] = {vx.x, vx.y, vx.z, vx.w};
    float ry[4] = {vy.x, vy.y, vy.z, vy.w};
    float rz[4] = {vz.x, vz.y, vz.z, vz.w};

    // ---- Phase A: per-voxel weights (OOB folded in) + pair-base offsets ----
    // [R2-verified math, bit-identical reordering only]
    float ax0[4], ax1[4], ay0[4], ay1[4], az0[4], az1[4];
    int   off00[4], off01[4], off10[4], off11[4];
    bool  zlo[4], zhi[4];

    #pragma unroll
    for (int j = 0; j < 4; ++j) {
        float x = rx[j] + (float)(w + 1);
        float y = ry[j] + (float)(h + 1);
        float z = rz[j] + (float)(d0 + j + 1);

        int fx = (int)floorf(x);
        int fy = (int)floorf(y);
        int fz = (int)floorf(z);

        // padded-coord clip [0, 193]
        int x0 = min(max(fx, 0), W + 1), x1 = min(max(fx + 1, 0), W + 1);
        int y0 = min(max(fy, 0), H + 1), y1 = min(max(fy + 1, 0), H + 1);
        int z0 = min(max(fz, 0), D + 1), z1 = min(max(fz + 1, 0), D + 1);

        float dx = (float)x1 - x;
        float dy = (float)y1 - y;
        float dz = (float)z1 - z;

        // unpadded indices
        int xi0 = x0 - 1, xi1 = x1 - 1;
        int yi0 = y0 - 1, yi1 = y1 - 1;
        int zi  = z0 - 1, zj  = z1 - 1;

        // fold OOB-zero into weights
        ax0[j] = ((unsigned)xi0 < (unsigned)W) ? dx          : 0.0f;
        ax1[j] = ((unsigned)xi1 < (unsigned)W) ? 1.0f - dx   : 0.0f;
        ay0[j] = ((unsigned)yi0 < (unsigned)H) ? dy          : 0.0f;
        ay1[j] = ((unsigned)yi1 < (unsigned)H) ? 1.0f - dy   : 0.0f;
        az0[j] = ((unsigned)zi  < (unsigned)D) ? dz          : 0.0f;
        az1[j] = ((unsigned)zj  < (unsigned)D) ? 1.0f - dz   : 0.0f;

        // clamped addresses (loads always legal; bogus values killed by zero weights)
        int xc0 = min(max(xi0, 0), W - 1), xc1 = min(max(xi1, 0), W - 1);
        int yc0 = min(max(yi0, 0), H - 1), yc1 = min(max(yi1, 0), H - 1);
        int zc  = min(max(zi, 0), D - 2);          // pair load [zc, zc+1] always in-bounds

        zlo[j] = (zi <= D - 2);   // z0 value at pair.x, else pair.y (zi == 191 case)
        zhi[j] = (zi >= 0);       // z1 value at pair.y, else pair.x (zi == -1 case)

        off00[j] = (yc0 * W + xc0) * D + zc;
        off01[j] = (yc0 * W + xc1) * D + zc;
        off10[j] = (yc1 * W + xc0) * D + zc;
        off11[j] = (yc1 * W + xc1) * D + zc;
    }

    // ---- Phase B: issue ALL 16 pair-gathers ----
    f2u p00[4], p01[4], p10[4], p11[4];
    #pragma unroll
    for (int j = 0; j < 4; ++j) {
        p00[j] = *reinterpret_cast<const f2u*>(I + off00[j]);
        p01[j] = *reinterpret_cast<const f2u*>(I + off01[j]);
        p10[j] = *reinterpret_cast<const f2u*>(I + off10[j]);
        p11[j] = *reinterpret_cast<const f2u*>(I + off11[j]);
    }

    // Pin the batch: loads cannot sink below, consumers cannot hoist above.
    // This is the single change vs the (passing) R2 kernel: forces ~16
    // gathers/wave in flight instead of the compiler's serialized 2-4.
    __builtin_amdgcn_sched_barrier(0);

    // ---- Phase C: weighted sum (R2-verified) ----
    float ro[4];
    #pragma unroll
    for (int j = 0; j < 4; ++j) {
        float v000 = zlo[j] ? p00[j].x : p00[j].y;   // (y0,x0,z0)
        float v001 = zhi[j] ? p00[j].y : p00[j].x;   // (y0,x0,z1)
        float v010 = zlo[j] ? p01[j].x : p01[j].y;   // (y0,x1,z0)
        float v011 = zhi[j] ? p01[j].y : p01[j].x;
        float v100 = zlo[j] ? p10[j].x : p10[j].y;   // (y1,x0,z0)
        float v101 = zhi[j] ? p10[j].y : p10[j].x;
        float v110 = zlo[j] ? p11[j].x : p11[j].y;   // (y1,x1,z0)
        float v111 = zhi[j] ? p11[j].y : p11[j].x;

        float s00 = az0[j] * v000 + az1[j] * v001;   // x0,y0
        float s01 = az0[j] * v010 + az1[j] * v011;   // x1,y0
        float s10 = az0[j] * v100 + az1[j] * v101;   // x0,y1
        float s11 = az0[j] * v110 + az1[j] * v111;   // x1,y1

        ro[j] = ay0[j] * (ax0[j] * s00 + ax1[j] * s01)
              + ay1[j] * (ax0[j] * s10 + ax1[j] * s11);
    }

    reinterpret_cast<float4*>(out)[t] = make_float4(ro[0], ro[1], ro[2], ro[3]);
}

extern "C" void kernel_launch(void* const* d_in, const int* in_sizes, int n_in,
                              void* d_out, int out_size, void* d_ws, size_t ws_size,
                              hipStream_t stream) {
    const float* I   = (const float*)d_in[0];
    const float* dxt = (const float*)d_in[1];
    const float* dyt = (const float*)d_in[2];
    const float* dzt = (const float*)d_in[3];
    float* out = (float*)d_out;

    int total = N / 4;
    int threads = 256;
    int blocks = total / threads;    // exact: 1728... (884736*? ) N/4/256 = 1728
    hipLaunchKernelGGL(st_gather, dim3(blocks), dim3(threads), 0, stream,
                       I, dxt, dyt, dzt, out);
}

// Round 11
// 49.997 us; speedup vs baseline: 1.3091x; 1.3091x over previous
//
#include <hip/hip_runtime.h>

constexpr int H = 192, W = 192, D = 192;
constexpr int BH = 16, BW = 16, BZ = 16;     // output tile per block
constexpr int TY = 24, TX = 24, TZ = 28;     // staged: x/y halo -4..+19, z -4..+23
constexpr int TILE_N = TY * TX * TZ;         // 16128 dwords = 63 KB -> 2 blocks/CU
constexpr int NINSTR = TY * TX * (TZ / 4) / 64;   // 63 wave-instructions of 64 chunks

// Exact reference semantics for one voxel, all-global (fallback path).
__device__ __forceinline__ float ref_voxel(const float* __restrict__ I,
                                           float x, float y, float zf)
{
    int fx = (int)floorf(x), fy = (int)floorf(y), fz = (int)floorf(zf);
    int x0 = min(max(fx, 0), W + 1), x1 = min(max(fx + 1, 0), W + 1);
    int y0 = min(max(fy, 0), H + 1), y1 = min(max(fy + 1, 0), H + 1);
    int zp0 = min(max(fz, 0), D + 1), zp1 = min(max(fz + 1, 0), D + 1);
    float dx = (float)x1 - x, dy = (float)y1 - y, dz = (float)zp1 - zf;
    int xi0 = x0 - 1, xi1 = x1 - 1, yi0 = y0 - 1, yi1 = y1 - 1;
    int zi = zp0 - 1, zj = zp1 - 1;
    float ax0 = ((unsigned)xi0 < (unsigned)W) ? dx       : 0.f;
    float ax1 = ((unsigned)xi1 < (unsigned)W) ? 1.f - dx : 0.f;
    float ay0 = ((unsigned)yi0 < (unsigned)H) ? dy       : 0.f;
    float ay1 = ((unsigned)yi1 < (unsigned)H) ? 1.f - dy : 0.f;
    float az0 = ((unsigned)zi  < (unsigned)D) ? dz       : 0.f;
    float az1 = ((unsigned)zj  < (unsigned)D) ? 1.f - dz : 0.f;
    int xc0 = min(max(xi0, 0), W - 1), xc1 = min(max(xi1, 0), W - 1);
    int yc0 = min(max(yi0, 0), H - 1), yc1 = min(max(yi1, 0), H - 1);
    int zc0 = min(max(zi, 0), D - 1),  zc1 = min(max(zj, 0), D - 1);
    const float* r00 = I + (yc0 * W + xc0) * D;
    const float* r01 = I + (yc0 * W + xc1) * D;
    const float* r10 = I + (yc1 * W + xc0) * D;
    const float* r11 = I + (yc1 * W + xc1) * D;
    float s00 = az0 * r00[zc0] + az1 * r00[zc1];
    float s01 = az0 * r01[zc0] + az1 * r01[zc1];
    float s10 = az0 * r10[zc0] + az1 * r10[zc1];
    float s11 = az0 * r11[zc0] + az1 * r11[zc1];
    return ay0 * (ax0 * s00 + ax1 * s01) + ay1 * (ax0 * s10 + ax1 * s11);
}

__global__ __launch_bounds__(512) void st_tile(
    const float* __restrict__ I,
    const float* __restrict__ dxt,
    const float* __restrict__ dyt,
    const float* __restrict__ dzt,
    float* __restrict__ out)
{
    __shared__ float tile[TILE_N];   // 63 KB -> 2 blocks/CU

    const int tid = threadIdx.x;
    const int bx = blockIdx.x, by = blockIdx.y, bz = blockIdx.z;
    const int w0 = bx * BW, h0 = by * BH, z0 = bz * BZ;
    const int xg0 = w0 - 4, yg0 = h0 - 4, zg0 = z0 - 4;

    // ---- staging: global_load_lds, per-lane CLAMPED source, linear LDS dest ----
    // chunk c: row = c/7 (= ry*24+rx), z-seg = (c%7)*4; dest dword = c*4 = row*28+seg.
    // TZ=28 row stride: 16 stride-28 lanes span 8 banks -> 2-way (free) vs TZ=24's 4-way.
    {
        const unsigned wv = tid >> 6, lane = tid & 63;
        for (unsigned i = wv; i < (unsigned)NINSTR; i += 8) {
            unsigned c = i * 64u + lane;
            unsigned row = c / 7u;
            unsigned s = c - row * 7u;
            unsigned ry = row / 24u;
            unsigned rx = row - ry * 24u;
            int gy = min(max(yg0 + (int)ry, 0), H - 1);
            int gx = min(max(xg0 + (int)rx, 0), W - 1);
            int zs = min(max(zg0 + (int)(s * 4u), 0), D - 4);
            const float* src = I + ((gy * W + gx) * D + zs);
            __builtin_amdgcn_global_load_lds(
                (const __attribute__((address_space(1))) void*)src,
                (__attribute__((address_space(3))) void*)(tile + i * 256u),
                16, 0, 0);
        }
    }

    // displacement loads (in flight alongside staging; drained together)
    const int zq = tid & 3, wloc = (tid >> 2) & 15, hl0 = tid >> 6;
    const int wg = w0 + wloc;
    float4 vx[2], vy[2], vz[2];
    #pragma unroll
    for (int k = 0; k < 2; ++k) {
        int hg = h0 + hl0 + 8 * k;
        int t4 = (hg * W + wg) * (D / 4) + (z0 >> 2) + zq;
        vx[k] = reinterpret_cast<const float4*>(dxt)[t4];
        vy[k] = reinterpret_cast<const float4*>(dyt)[t4];
        vz[k] = reinterpret_cast<const float4*>(dzt)[t4];
    }

    asm volatile("s_waitcnt vmcnt(0)" ::: "memory");
    __syncthreads();

    // block-uniform fast-path bounds [R8/R9-verified]
    const int lox = max(0, -xg0), hix = min(TX - 2, 190 - xg0);
    const int loy = max(0, -yg0), hiy = min(TY - 2, 190 - yg0);
    const int loz = max(0, -zg0), hiz = min(TZ - 2, 190 - zg0);

    float ro[2][4];
    #pragma unroll
    for (int k = 0; k < 2; ++k) {
        const int hg = h0 + hl0 + 8 * k;
        const int hl = hl0 + 8 * k;
        float rxj[4] = {vx[k].x, vx[k].y, vx[k].z, vx[k].w};
        float ryj[4] = {vy[k].x, vy[k].y, vy[k].z, vy[k].w};
        float rzj[4] = {vz[k].x, vz[k].y, vz[k].z, vz[k].w};

        // ---- phase A: local coords + fast flags ----
        int   lxa[4], lya[4], lza[4];
        float txa[4], tya[4], tza[4];
        bool  fa[4];
        #pragma unroll
        for (int j = 0; j < 4; ++j) {
            float xl = rxj[j] + (float)(wloc + 4);
            float yl = ryj[j] + (float)(hl + 4);
            float zl = rzj[j] + (float)(zq * 4 + j + 4);
            float fxf = floorf(xl), fyf = floorf(yl), fzf = floorf(zl);
            lxa[j] = (int)fxf; lya[j] = (int)fyf; lza[j] = (int)fzf;
            txa[j] = xl - fxf; tya[j] = yl - fyf; tza[j] = zl - fzf;
            fa[j] = ((unsigned)(lxa[j] - lox) <= (unsigned)(hix - lox))
                  & ((unsigned)(lya[j] - loy) <= (unsigned)(hiy - loy))
                  & ((unsigned)(lza[j] - loz) <= (unsigned)(hiz - loz));
        }

        if (__builtin_expect(__all(fa[0] & fa[1] & fa[2] & fa[3]), 1)) {
            // ---- fast path: no clamps, plain frac weights (R8/R9-verified) ----
            #pragma unroll
            for (int j = 0; j < 4; ++j) {
                int b = (lya[j] * TX + lxa[j]) * TZ + lza[j];
                float a0 = tile[b],                a1 = tile[b + 1];
                float b0 = tile[b + TZ],           b1 = tile[b + TZ + 1];
                float c0 = tile[b + TX * TZ],      c1 = tile[b + TX * TZ + 1];
                float d0 = tile[b + TX * TZ + TZ], d1 = tile[b + TX * TZ + TZ + 1];
                float wz0 = 1.f - tza[j], wz1 = tza[j];
                float wx0 = 1.f - txa[j], wx1 = txa[j];
                float wy0 = 1.f - tya[j], wy1 = tya[j];
                float s00 = wz0 * a0 + wz1 * a1;
                float s01 = wz0 * b0 + wz1 * b1;
                float s10 = wz0 * c0 + wz1 * c1;
                float s11 = wz0 * d0 + wz1 * d1;
                ro[k][j] = wy0 * (wx0 * s00 + wx1 * s01) + wy1 * (wx0 * s10 + wx1 * s11);
            }
        } else {
            // ---- full path: reference clamp semantics (R6/R7-verified) ----
            #pragma unroll
            for (int j = 0; j < 4; ++j) {
                const int zv = z0 + zq * 4 + j;
                float x  = rxj[j] + (float)(wg + 1);
                float y  = ryj[j] + (float)(hg + 1);
                float zf = rzj[j] + (float)(zv + 1);

                int fx = (int)floorf(x), fy = (int)floorf(y), fz = (int)floorf(zf);
                int x0 = min(max(fx, 0), W + 1), x1 = min(max(fx + 1, 0), W + 1);
                int y0 = min(max(fy, 0), H + 1), y1 = min(max(fy + 1, 0), H + 1);
                int zp0 = min(max(fz, 0), D + 1), zp1 = min(max(fz + 1, 0), D + 1);

                float dx = (float)x1 - x, dy = (float)y1 - y, dz = (float)zp1 - zf;

                int xi0 = x0 - 1, xi1 = x1 - 1, yi0 = y0 - 1, yi1 = y1 - 1;
                int zi = zp0 - 1, zj2 = zp1 - 1;

                float ax0 = ((unsigned)xi0 < (unsigned)W) ? dx       : 0.f;
                float ax1 = ((unsigned)xi1 < (unsigned)W) ? 1.f - dx : 0.f;
                float ay0 = ((unsigned)yi0 < (unsigned)H) ? dy       : 0.f;
                float ay1 = ((unsigned)yi1 < (unsigned)H) ? 1.f - dy : 0.f;
                float az0 = ((unsigned)zi  < (unsigned)D) ? dz       : 0.f;
                float az1 = ((unsigned)zj2 < (unsigned)D) ? 1.f - dz : 0.f;

                int xc0 = min(max(xi0, 0), W - 1), xc1 = min(max(xi1, 0), W - 1);
                int yc0 = min(max(yi0, 0), H - 1), yc1 = min(max(yi1, 0), H - 1);
                int zc  = min(max(zi, 0), D - 2);

                bool zlo = (zi <= D - 2);
                bool zhi = (zi >= 0);

                int lx0 = xc0 - xg0, lx1 = xc1 - xg0;
                int ly0 = yc0 - yg0, ly1 = yc1 - yg0;
                int lz  = zc - zg0;

                bool ok = ((unsigned)lx0 <= (unsigned)(TX - 1))
                        & ((unsigned)lx1 <= (unsigned)(TX - 1))
                        & ((unsigned)ly0 <= (unsigned)(TY - 1))
                        & ((unsigned)ly1 <= (unsigned)(TY - 1))
                        & ((unsigned)lz  <= (unsigned)(TZ - 2));

                int b00 = min(max((ly0 * TX + lx0) * TZ + lz, 0), TILE_N - 2);
                int b01 = min(max((ly0 * TX + lx1) * TZ + lz, 0), TILE_N - 2);
                int b10 = min(max((ly1 * TX + lx0) * TZ + lz, 0), TILE_N - 2);
                int b11 = min(max((ly1 * TX + lx1) * TZ + lz, 0), TILE_N - 2);

                float a0 = tile[b00], a1 = tile[b00 + 1];
                float b0 = tile[b01], b1 = tile[b01 + 1];
                float c0 = tile[b10], c1 = tile[b10 + 1];
                float d0 = tile[b11], d1 = tile[b11 + 1];

                float v000 = zlo ? a0 : a1, v001 = zhi ? a1 : a0;
                float v010 = zlo ? b0 : b1, v011 = zhi ? b1 : b0;
                float v100 = zlo ? c0 : c1, v101 = zhi ? c1 : c0;
                float v110 = zlo ? d0 : d1, v111 = zhi ? d1 : d0;
                float s00 = az0 * v000 + az1 * v001;
                float s01 = az0 * v010 + az1 * v011;
                float s10 = az0 * v100 + az1 * v101;
                float s11 = az0 * v110 + az1 * v111;
                float r = ay0 * (ax0 * s00 + ax1 * s01)
                        + ay1 * (ax0 * s10 + ax1 * s11);

                ro[k][j] = __builtin_expect(ok, 1) ? r : ref_voxel(I, x, y, zf);
            }
        }
    }

    #pragma unroll
    for (int k = 0; k < 2; ++k) {
        int hg = h0 + hl0 + 8 * k;
        int t4 = (hg * W + wg) * (D / 4) + (z0 >> 2) + zq;
        reinterpret_cast<float4*>(out)[t4] =
            make_float4(ro[k][0], ro[k][1], ro[k][2], ro[k][3]);
    }
}

extern "C" void kernel_launch(void* const* d_in, const int* in_sizes, int n_in,
                              void* d_out, int out_size, void* d_ws, size_t ws_size,
                              hipStream_t stream) {
    const float* I   = (const float*)d_in[0];
    const float* dxt = (const float*)d_in[1];
    const float* dyt = (const float*)d_in[2];
    const float* dzt = (const float*)d_in[3];
    float* out = (float*)d_out;

    dim3 grid(W / BW, H / BH, D / BZ);   // 12 x 12 x 12
    hipLaunchKernelGGL(st_tile, grid, dim3(512), 0, stream,
                       I, dxt, dyt, dzt, out);
}